// Round 14
// baseline (212.094 us; speedup 1.0000x reference)
//
#include <hip/hip_runtime.h>

typedef unsigned short ushort_t;
typedef __attribute__((ext_vector_type(8))) short bf16x8;
typedef __attribute__((ext_vector_type(4))) float f32x4;
typedef __attribute__((ext_vector_type(16))) float f32x16;
typedef __attribute__((ext_vector_type(4))) unsigned short ushort4v;
typedef __attribute__((ext_vector_type(4))) unsigned int uint4v;

__device__ __forceinline__ ushort_t f2bf(float f) {
  unsigned u = __float_as_uint(f);
  u += 0x7FFFu + ((u >> 16) & 1u);
  return (ushort_t)(u >> 16);
}

__device__ __forceinline__ unsigned cvt_pk(float lo, float hi) {
  unsigned r;
  asm("v_cvt_pk_bf16_f32 %0, %1, %2" : "=v"(r) : "v"(lo), "v"(hi));
  return r;
}

__device__ __forceinline__ float fast_exp2(float x) {
  float r;
  asm("v_exp_f32 %0, %1" : "=v"(r) : "v"(x));
  return r;
}

__device__ __forceinline__ void gload16(ushort_t* lds, const ushort_t* g) {
  __builtin_amdgcn_global_load_lds(
      (const __attribute__((address_space(1))) unsigned int*)g,
      (__attribute__((address_space(3))) unsigned int*)lds, 16, 0, 0);
}

// ---------------- weight cast (4 tensors, one launch) ----------------
__global__ void cast_w4(const float* __restrict__ s0, const float* __restrict__ s1,
                        const float* __restrict__ s2, const float* __restrict__ s3,
                        ushort_t* __restrict__ dst, int n4) {
  int i = blockIdx.x * blockDim.x + threadIdx.x;
  if (i >= n4) return;
  int z = blockIdx.y;
  const float* s = (z == 0) ? s0 : (z == 1) ? s1 : (z == 2) ? s2 : s3;
  float4 f = ((const float4*)s)[i];
  ushort4v o;
  o.x = f2bf(f.x); o.y = f2bf(f.y); o.z = f2bf(f.z); o.w = f2bf(f.w);
  ((ushort4v*)(dst + (size_t)z * n4 * 4))[i] = o;
}

// ---------------- fused QKV projection GEMM (double-buffered) ----------------
__global__ __launch_bounds__(256, 2)
void qkv_gemm(const float* __restrict__ qa, const float* __restrict__ ka,
              const float* __restrict__ va, const ushort_t* __restrict__ Wb,
              ushort_t* __restrict__ QKp, ushort_t* __restrict__ Vt,
              float qscale) {
  const int M = 8192, N = 1024, K = 1024;
  __shared__ __align__(16) ushort_t As[2][128 * 64];
  __shared__ __align__(16) ushort_t Bs[2][128 * 64];
  const int tid = threadIdx.x;
  const int wave = tid >> 6, lane = tid & 63;
  const int wr = wave >> 1, wc = wave & 1;
  const int frow = lane & 15, g = lane >> 4;
  const int r8 = lane >> 3, c8 = lane & 7;
  const int m0 = blockIdx.x * 128, n0 = blockIdx.y * 128;
  const int z = blockIdx.z;

  const float* Asrc = (z == 0) ? qa : (z == 1) ? ka : va;
  const float scale = (z == 0) ? qscale : 1.0f;

  f32x4 acc[4][4] = {};

  const int sc = (c8 ^ r8) << 3;
  const ushort_t* Bb = Wb + (size_t)z * N * K + (size_t)(n0 + wave * 32 + r8) * K + sc;
  const float* Af = Asrc + (size_t)(m0 + wave * 32 + r8) * K + sc;

  float aF[32];
  auto loadA = [&](int t) {
#pragma unroll
    for (int j = 0; j < 4; ++j) {
      *(float4*)&aF[j * 8]     = *(const float4*)(Af + (size_t)j * 8 * K + t * 64);
      *(float4*)&aF[j * 8 + 4] = *(const float4*)(Af + (size_t)j * 8 * K + t * 64 + 4);
    }
  };
  auto writeA = [&](int sel) {
    ushort_t* AsW = &As[sel][(wave * 32) * 64];
#pragma unroll
    for (int j = 0; j < 4; ++j) {
      uint4v w;
      w[0] = cvt_pk(aF[j * 8 + 0], aF[j * 8 + 1]);
      w[1] = cvt_pk(aF[j * 8 + 2], aF[j * 8 + 3]);
      w[2] = cvt_pk(aF[j * 8 + 4], aF[j * 8 + 5]);
      w[3] = cvt_pk(aF[j * 8 + 6], aF[j * 8 + 7]);
      *(uint4v*)&AsW[j * 8 * 64 + lane * 8] = w;
    }
  };
  auto stageB = [&](int t, int sel) {
    ushort_t* BsW = &Bs[sel][(wave * 32) * 64];
#pragma unroll
    for (int j = 0; j < 4; ++j)
      gload16(BsW + j * 8 * 64, Bb + (size_t)j * 8 * K + t * 64);
  };

  loadA(0);
  writeA(0);
  stageB(0, 0);
  loadA(1);
  __syncthreads();

  const int NT = K / 64;
  for (int t = 0; t < NT; ++t) {
    const int cur = t & 1, nxt = cur ^ 1;
    if (t < NT - 1) {
      writeA(nxt);
      stageB(t + 1, nxt);
      if (t < NT - 2) loadA(t + 2);
    }

    bf16x8 af[4][2], bfr[4][2];
#pragma unroll
    for (int mi = 0; mi < 4; ++mi) {
      int row = wr * 64 + mi * 16 + frow;
#pragma unroll
      for (int ki = 0; ki < 2; ++ki)
        af[mi][ki] = *(const bf16x8*)&As[cur][row * 64 + (((ki * 4 + g) ^ (row & 7)) << 3)];
    }
#pragma unroll
    for (int nf = 0; nf < 4; ++nf) {
      int row = wc * 64 + nf * 16 + frow;
#pragma unroll
      for (int ki = 0; ki < 2; ++ki)
        bfr[nf][ki] = *(const bf16x8*)&Bs[cur][row * 64 + (((ki * 4 + g) ^ (row & 7)) << 3)];
    }
#pragma unroll
    for (int ki = 0; ki < 2; ++ki)
#pragma unroll
      for (int mi = 0; mi < 4; ++mi)
#pragma unroll
        for (int nf = 0; nf < 4; ++nf)
          acc[mi][nf] = __builtin_amdgcn_mfma_f32_16x16x32_bf16(
              af[mi][ki], bfr[nf][ki], acc[mi][nf], 0, 0, 0);

    __syncthreads();
  }

#pragma unroll
  for (int mi = 0; mi < 4; ++mi)
#pragma unroll
    for (int nf = 0; nf < 4; ++nf)
#pragma unroll
      for (int r = 0; r < 4; ++r) {
        int m = m0 + wr * 64 + mi * 16 + g * 4 + r;
        int n = n0 + wc * 64 + nf * 16 + frow;
        float v = acc[mi][nf][r] * scale;
        if (z == 2) {
          int b = m >> 11, s = m & 2047, h = n >> 6, dk = n & 63;
          Vt[(((size_t)((b * 16 + h) * 64 + dk)) << 11) + s] = f2bf(v);
        } else {
          QKp[(size_t)z * M * N + (size_t)m * N + n] = f2bf(v);
        }
      }
}

// ---------------- output projection GEMM (bf16 A, f32 C, dbuf) ----------------
__global__ __launch_bounds__(256, 2)
void gemm_out(const ushort_t* __restrict__ A, const ushort_t* __restrict__ B,
              float* __restrict__ Cp, int M, int N, int K) {
  __shared__ __align__(16) ushort_t As[2][128 * 64];
  __shared__ __align__(16) ushort_t Bs[2][128 * 64];
  const int tid = threadIdx.x;
  const int wave = tid >> 6, lane = tid & 63;
  const int wr = wave >> 1, wc = wave & 1;
  const int frow = lane & 15, g = lane >> 4;
  const int r8 = lane >> 3, c8 = lane & 7;
  const int m0 = blockIdx.x * 128, n0 = blockIdx.y * 128;

  f32x4 acc[4][4] = {};

  const int sc = (c8 ^ r8) << 3;
  const ushort_t* Ab = A + (size_t)(m0 + wave * 32 + r8) * K + sc;
  const ushort_t* Bb = B + (size_t)(n0 + wave * 32 + r8) * K + sc;

  auto stage = [&](int t, int sel) {
    ushort_t* AsW = &As[sel][(wave * 32) * 64];
    ushort_t* BsW = &Bs[sel][(wave * 32) * 64];
#pragma unroll
    for (int j = 0; j < 4; ++j) {
      gload16(AsW + j * 8 * 64, Ab + (size_t)j * 8 * K + t * 64);
      gload16(BsW + j * 8 * 64, Bb + (size_t)j * 8 * K + t * 64);
    }
  };

  stage(0, 0);
  __syncthreads();

  const int NT = K / 64;
  for (int t = 0; t < NT; ++t) {
    const int cur = t & 1;
    if (t < NT - 1) stage(t + 1, cur ^ 1);

    bf16x8 af[4][2], bfr[4][2];
#pragma unroll
    for (int mi = 0; mi < 4; ++mi) {
      int row = wr * 64 + mi * 16 + frow;
#pragma unroll
      for (int ki = 0; ki < 2; ++ki)
        af[mi][ki] = *(const bf16x8*)&As[cur][row * 64 + (((ki * 4 + g) ^ (row & 7)) << 3)];
    }
#pragma unroll
    for (int nf = 0; nf < 4; ++nf) {
      int row = wc * 64 + nf * 16 + frow;
#pragma unroll
      for (int ki = 0; ki < 2; ++ki)
        bfr[nf][ki] = *(const bf16x8*)&Bs[cur][row * 64 + (((ki * 4 + g) ^ (row & 7)) << 3)];
    }
#pragma unroll
    for (int ki = 0; ki < 2; ++ki)
#pragma unroll
      for (int mi = 0; mi < 4; ++mi)
#pragma unroll
        for (int nf = 0; nf < 4; ++nf)
          acc[mi][nf] = __builtin_amdgcn_mfma_f32_16x16x32_bf16(
              af[mi][ki], bfr[nf][ki], acc[mi][nf], 0, 0, 0);

    __syncthreads();
  }

#pragma unroll
  for (int mi = 0; mi < 4; ++mi)
#pragma unroll
    for (int nf = 0; nf < 4; ++nf)
#pragma unroll
      for (int r = 0; r < 4; ++r) {
        int m = m0 + wr * 64 + mi * 16 + g * 4 + r;
        int n = n0 + wc * 64 + nf * 16 + frow;
        Cp[(size_t)m * N + n] = acc[mi][nf][r];
      }
}

// ---------------- flash attention: 32x32 MFMA, P in registers ----------------
// R7-VERBATIM kernel body (proven CORRECT in R7; slow there only due to
// launch_bounds(256,4) forcing a 128-VGPR cap -> accumulator spill).
// ONLY change: launch_bounds -> (256,2) = natural register allocation.
// Geometry: 128 q-rows/block (4 waves x 1 32-q subtile), grid 1024 ->
// 4 blocks/CU (fixes R6's grid-limited 2/CU). XCD-bijective swizzle: all 16
// blocks of a head share d%8 -> one XCD; per-XCD K/V = 8 heads x 512KB = L2.
// Row-sum via ones-MFMA: lones has identical row mapping as oacc -> the
// normalize is a per-register divide (no shuffles).
__global__ __launch_bounds__(256, 2)
void attn_kernel(const ushort_t* __restrict__ Qp, const ushort_t* __restrict__ Kp,
                 const ushort_t* __restrict__ Vt, ushort_t* __restrict__ Xb) {
  __shared__ __align__(16) ushort_t Ks[2][64 * 64];   // [buf][key][d] swizzled
  __shared__ __align__(16) ushort_t Vs[2][64 * 64];   // [buf][d][key] swizzled

  const int tid = threadIdx.x;
  const int wave = tid >> 6, lane = tid & 63;
  const int l31 = lane & 31, h = lane >> 5;
  const int f8 = lane >> 3, c8 = lane & 7;

  const int d = blockIdx.x;                  // 0..1023
  const int bh = ((d >> 7) << 3) | (d & 7);  // same-head blocks share d%8 (XCD)
  const int qt = (d >> 3) & 15;
  const int b = bh >> 4, hd = bh & 15;
  const int q0 = qt * 128 + wave * 32;

  // Q fragments: qf[ki] = Q[q0+l31][hd*64 + 16ki + 8h .. +7]
  bf16x8 qf[4];
  {
    const ushort_t* qb_ = Qp + (size_t)(b * 2048 + q0 + l31) * 1024 + hd * 64 + 8 * h;
#pragma unroll
    for (int ki = 0; ki < 4; ++ki)
      qf[ki] = *(const bf16x8*)(qb_ + 16 * ki);
  }

  const short one_bf = (short)0x3F80;
  const bf16x8 vones = {one_bf, one_bf, one_bf, one_bf,
                        one_bf, one_bf, one_bf, one_bf};

  f32x16 oacc[2] = {};
  f32x16 lones = {};

  const ushort_t* Kbase = Kp + (size_t)(b * 2048) * 1024 + hd * 64;
  const ushort_t* Vbase = Vt + ((size_t)(bh * 64) << 11);

  auto stage = [&](int kt, int sel) {
#pragma unroll
    for (int j = 0; j < 2; ++j) {
      int row = wave * 16 + j * 8 + f8;  // row&7 == f8
      gload16(&Ks[sel][(wave * 16 + j * 8) * 64],
              Kbase + (size_t)(kt * 64 + row) * 1024 + ((c8 ^ f8) << 3));
      gload16(&Vs[sel][(wave * 16 + j * 8) * 64],
              Vbase + ((size_t)row << 11) + kt * 64 + ((c8 ^ f8) << 3));
    }
  };

  stage(0, 0);

  for (int kt = 0; kt < 32; ++kt) {
    const int cur = kt & 1;
    __syncthreads();                       // vmcnt(0) drain: stage(kt) landed
    if (kt < 31) stage(kt + 1, cur ^ 1);   // prefetch under compute

    // K frags: kf[c][ki] = K[32c+l31][16ki+8h..+7] (A-operand, row=key)
    bf16x8 kf[2][4];
#pragma unroll
    for (int c = 0; c < 2; ++c)
#pragma unroll
      for (int ki = 0; ki < 4; ++ki) {
        int row = c * 32 + l31;
        kf[c][ki] = *(const bf16x8*)&Ks[cur][row * 64 + (((2 * ki + h) ^ (row & 7)) << 3)];
      }
    // V frags: vf[kc][db] = V[16kc+8h..+7][32db+l31] (B-operand) from Vs[d][key]
    bf16x8 vf[4][2];
#pragma unroll
    for (int kc = 0; kc < 4; ++kc)
#pragma unroll
      for (int db = 0; db < 2; ++db) {
        int row = db * 32 + l31;
        vf[kc][db] = *(const bf16x8*)&Vs[cur][row * 64 + (((2 * kc + h) ^ (row & 7)) << 3)];
      }

    // S^T[key][q]: D col=q=l31, row=key=(reg&3)+8*(reg>>2)+4h+32c
    f32x16 sacc[2];
    __builtin_amdgcn_s_setprio(1);
#pragma unroll
    for (int c = 0; c < 2; ++c) {
      sacc[c] = __builtin_amdgcn_mfma_f32_32x32x16_bf16(
          kf[c][0], qf[0], (f32x16)(0.0f), 0, 0, 0);
#pragma unroll
      for (int ki = 1; ki < 4; ++ki)
        sacc[c] = __builtin_amdgcn_mfma_f32_32x32x16_bf16(
            kf[c][ki], qf[ki], sacc[c], 0, 0, 0);
    }
    __builtin_amdgcn_s_setprio(0);

    // p = exp2(s) in place (row sums come free from the ones-MFMA below)
#pragma unroll
    for (int c = 0; c < 2; ++c)
#pragma unroll
      for (int r = 0; r < 16; r += 4) {
        sacc[c][r]     = fast_exp2(sacc[c][r]);
        sacc[c][r + 1] = fast_exp2(sacc[c][r + 1]);
        sacc[c][r + 2] = fast_exp2(sacc[c][r + 2]);
        sacc[c][r + 3] = fast_exp2(sacc[c][r + 3]);
      }

    // lane holds 4-elem halves (offset 4h) of every 8-key block;
    // swap even/odd-block halves with partner lane l^32 -> consecutive 8.
    bf16x8 pfrag[4];
#pragma unroll
    for (int kc = 0; kc < 4; ++kc) {
      const int e = 2 * kc, o = 2 * kc + 1;
      const int ce = e >> 2, me = e & 3, co = o >> 2, mo = o & 3;
      unsigned x0, x1, y0, y1;
      x0 = cvt_pk(sacc[ce][4 * me],     sacc[ce][4 * me + 1]);
      x1 = cvt_pk(sacc[ce][4 * me + 2], sacc[ce][4 * me + 3]);
      y0 = cvt_pk(sacc[co][4 * mo],     sacc[co][4 * mo + 1]);
      y1 = cvt_pk(sacc[co][4 * mo + 2], sacc[co][4 * mo + 3]);
      asm("v_permlane32_swap_b32 %0, %1" : "+v"(x0), "+v"(y0));
      asm("v_permlane32_swap_b32 %0, %1" : "+v"(x1), "+v"(y1));
      uint4v pu; pu[0] = x0; pu[1] = x1; pu[2] = y0; pu[3] = y1;
      pfrag[kc] = __builtin_bit_cast(bf16x8, pu);
    }

    // O[q][d] += P V ; row-sum l += P * ones (same D row-mapping as oacc)
    __builtin_amdgcn_s_setprio(1);
#pragma unroll
    for (int kc = 0; kc < 4; ++kc) {
      oacc[0] = __builtin_amdgcn_mfma_f32_32x32x16_bf16(
          pfrag[kc], vf[kc][0], oacc[0], 0, 0, 0);
      oacc[1] = __builtin_amdgcn_mfma_f32_32x32x16_bf16(
          pfrag[kc], vf[kc][1], oacc[1], 0, 0, 0);
      lones = __builtin_amdgcn_mfma_f32_32x32x16_bf16(
          pfrag[kc], vones, lones, 0, 0, 0);
    }
    __builtin_amdgcn_s_setprio(0);
  }

  // epilogue: per-register divide (lones row mapping == oacc row mapping)
  float linv[16];
#pragma unroll
  for (int r = 0; r < 16; ++r) linv[r] = 1.0f / lones[r];
#pragma unroll
  for (int db = 0; db < 2; ++db)
#pragma unroll
    for (int r = 0; r < 16; ++r) {
      int qrow = (r & 3) + 8 * (r >> 2) + 4 * h;   // D-row = q-local
      int grow = b * 2048 + q0 + qrow;
      int gcol = hd * 64 + db * 32 + l31;
      Xb[(size_t)grow * 1024 + gcol] = f2bf(oacc[db][r] * linv[r]);
    }
}

// ---------------- launch ----------------
extern "C" void kernel_launch(void* const* d_in, const int* in_sizes, int n_in,
                              void* d_out, int out_size, void* d_ws, size_t ws_size,
                              hipStream_t stream) {
  const float* q = (const float*)d_in[0];
  const float* k = (const float*)d_in[1];
  const float* v = (const float*)d_in[2];
  const float* wq = (const float*)d_in[3];
  const float* wk = (const float*)d_in[4];
  const float* wv = (const float*)d_in[5];
  const float* wo = (const float*)d_in[6];

  const int M = 8192, D = 1024;
  const size_t MD = (size_t)M * D;
  const size_t DD = (size_t)D * D;

  ushort_t* ws = (ushort_t*)d_ws;
  ushort_t* buf0 = ws;             // attn output
  ushort_t* Qp = buf0 + MD;        // Qp, Kp contiguous (qkv_gemm z<2)
  ushort_t* Kp = Qp + MD;
  ushort_t* Vt = Kp + MD;
  ushort_t* wqb = Vt + MD;         // 4 weight buffers contiguous
  ushort_t* wob = wqb + 3 * DD;

  // weights -> bf16 (one launch)
  {
    int n4 = (int)(DD / 4);
    dim3 gw((n4 + 255) / 256, 4);
    cast_w4<<<gw, 256, 0, stream>>>(wq, wk, wv, wo, wqb, n4);
  }

  // fused Q/K/V projections: grid (64,8,3) = 1536 blocks
  {
    dim3 gq(M / 128, D / 128, 3);
    qkv_gemm<<<gq, 256, 0, stream>>>(q, k, v, wqb, Qp, Vt,
                                     0.125f * 1.44269504f);
  }

  // attention -> buf0 (bf16); 1024 blocks, XCD-16 swizzle
  attn_kernel<<<1024, 256, 0, stream>>>(Qp, Kp, Vt, buf0);

  // output projection -> f32 out
  dim3 gg(M / 128, D / 128);
  gemm_out<<<gg, 256, 0, stream>>>(buf0, wob, (float*)d_out, M, D, D);
}

// Round 15
// 197.993 us; speedup vs baseline: 1.0712x; 1.0712x over previous
//
#include <hip/hip_runtime.h>

typedef unsigned short ushort_t;
typedef __attribute__((ext_vector_type(8))) short bf16x8;
typedef __attribute__((ext_vector_type(4))) float f32x4;
typedef __attribute__((ext_vector_type(16))) float f32x16;
typedef __attribute__((ext_vector_type(4))) unsigned short ushort4v;
typedef __attribute__((ext_vector_type(4))) unsigned int uint4v;

__device__ __forceinline__ ushort_t f2bf(float f) {
  unsigned u = __float_as_uint(f);
  u += 0x7FFFu + ((u >> 16) & 1u);
  return (ushort_t)(u >> 16);
}

__device__ __forceinline__ unsigned cvt_pk(float lo, float hi) {
  unsigned r;
  asm("v_cvt_pk_bf16_f32 %0, %1, %2" : "=v"(r) : "v"(lo), "v"(hi));
  return r;
}

__device__ __forceinline__ float fast_exp2(float x) {
  float r;
  asm("v_exp_f32 %0, %1" : "=v"(r) : "v"(x));
  return r;
}

__device__ __forceinline__ void gload16(ushort_t* lds, const ushort_t* g) {
  __builtin_amdgcn_global_load_lds(
      (const __attribute__((address_space(1))) unsigned int*)g,
      (__attribute__((address_space(3))) unsigned int*)lds, 16, 0, 0);
}

// ---------------- weight cast (4 tensors, one launch) ----------------
__global__ void cast_w4(const float* __restrict__ s0, const float* __restrict__ s1,
                        const float* __restrict__ s2, const float* __restrict__ s3,
                        ushort_t* __restrict__ dst, int n4) {
  int i = blockIdx.x * blockDim.x + threadIdx.x;
  if (i >= n4) return;
  int z = blockIdx.y;
  const float* s = (z == 0) ? s0 : (z == 1) ? s1 : (z == 2) ? s2 : s3;
  float4 f = ((const float4*)s)[i];
  ushort4v o;
  o.x = f2bf(f.x); o.y = f2bf(f.y); o.z = f2bf(f.z); o.w = f2bf(f.w);
  ((ushort4v*)(dst + (size_t)z * n4 * 4))[i] = o;
}

// ---------------- fused QKV projection GEMM (double-buffered) ----------------
__global__ __launch_bounds__(256, 2)
void qkv_gemm(const float* __restrict__ qa, const float* __restrict__ ka,
              const float* __restrict__ va, const ushort_t* __restrict__ Wb,
              ushort_t* __restrict__ QKp, ushort_t* __restrict__ Vt,
              float qscale) {
  const int M = 8192, N = 1024, K = 1024;
  __shared__ __align__(16) ushort_t As[2][128 * 64];
  __shared__ __align__(16) ushort_t Bs[2][128 * 64];
  const int tid = threadIdx.x;
  const int wave = tid >> 6, lane = tid & 63;
  const int wr = wave >> 1, wc = wave & 1;
  const int frow = lane & 15, g = lane >> 4;
  const int r8 = lane >> 3, c8 = lane & 7;
  const int m0 = blockIdx.x * 128, n0 = blockIdx.y * 128;
  const int z = blockIdx.z;

  const float* Asrc = (z == 0) ? qa : (z == 1) ? ka : va;
  const float scale = (z == 0) ? qscale : 1.0f;

  f32x4 acc[4][4] = {};

  const int sc = (c8 ^ r8) << 3;
  const ushort_t* Bb = Wb + (size_t)z * N * K + (size_t)(n0 + wave * 32 + r8) * K + sc;
  const float* Af = Asrc + (size_t)(m0 + wave * 32 + r8) * K + sc;

  float aF[32];
  auto loadA = [&](int t) {
#pragma unroll
    for (int j = 0; j < 4; ++j) {
      *(float4*)&aF[j * 8]     = *(const float4*)(Af + (size_t)j * 8 * K + t * 64);
      *(float4*)&aF[j * 8 + 4] = *(const float4*)(Af + (size_t)j * 8 * K + t * 64 + 4);
    }
  };
  auto writeA = [&](int sel) {
    ushort_t* AsW = &As[sel][(wave * 32) * 64];
#pragma unroll
    for (int j = 0; j < 4; ++j) {
      uint4v w;
      w[0] = cvt_pk(aF[j * 8 + 0], aF[j * 8 + 1]);
      w[1] = cvt_pk(aF[j * 8 + 2], aF[j * 8 + 3]);
      w[2] = cvt_pk(aF[j * 8 + 4], aF[j * 8 + 5]);
      w[3] = cvt_pk(aF[j * 8 + 6], aF[j * 8 + 7]);
      *(uint4v*)&AsW[j * 8 * 64 + lane * 8] = w;
    }
  };
  auto stageB = [&](int t, int sel) {
    ushort_t* BsW = &Bs[sel][(wave * 32) * 64];
#pragma unroll
    for (int j = 0; j < 4; ++j)
      gload16(BsW + j * 8 * 64, Bb + (size_t)j * 8 * K + t * 64);
  };

  loadA(0);
  writeA(0);
  stageB(0, 0);
  loadA(1);
  __syncthreads();

  const int NT = K / 64;
  for (int t = 0; t < NT; ++t) {
    const int cur = t & 1, nxt = cur ^ 1;
    if (t < NT - 1) {
      writeA(nxt);
      stageB(t + 1, nxt);
      if (t < NT - 2) loadA(t + 2);
    }

    bf16x8 af[4][2], bfr[4][2];
#pragma unroll
    for (int mi = 0; mi < 4; ++mi) {
      int row = wr * 64 + mi * 16 + frow;
#pragma unroll
      for (int ki = 0; ki < 2; ++ki)
        af[mi][ki] = *(const bf16x8*)&As[cur][row * 64 + (((ki * 4 + g) ^ (row & 7)) << 3)];
    }
#pragma unroll
    for (int nf = 0; nf < 4; ++nf) {
      int row = wc * 64 + nf * 16 + frow;
#pragma unroll
      for (int ki = 0; ki < 2; ++ki)
        bfr[nf][ki] = *(const bf16x8*)&Bs[cur][row * 64 + (((ki * 4 + g) ^ (row & 7)) << 3)];
    }
#pragma unroll
    for (int ki = 0; ki < 2; ++ki)
#pragma unroll
      for (int mi = 0; mi < 4; ++mi)
#pragma unroll
        for (int nf = 0; nf < 4; ++nf)
          acc[mi][nf] = __builtin_amdgcn_mfma_f32_16x16x32_bf16(
              af[mi][ki], bfr[nf][ki], acc[mi][nf], 0, 0, 0);

    __syncthreads();
  }

#pragma unroll
  for (int mi = 0; mi < 4; ++mi)
#pragma unroll
    for (int nf = 0; nf < 4; ++nf)
#pragma unroll
      for (int r = 0; r < 4; ++r) {
        int m = m0 + wr * 64 + mi * 16 + g * 4 + r;
        int n = n0 + wc * 64 + nf * 16 + frow;
        float v = acc[mi][nf][r] * scale;
        if (z == 2) {
          int b = m >> 11, s = m & 2047, h = n >> 6, dk = n & 63;
          Vt[(((size_t)((b * 16 + h) * 64 + dk)) << 11) + s] = f2bf(v);
        } else {
          QKp[(size_t)z * M * N + (size_t)m * N + n] = f2bf(v);
        }
      }
}

// ---------------- output projection GEMM (bf16 A, f32 C, dbuf) ----------------
__global__ __launch_bounds__(256, 2)
void gemm_out(const ushort_t* __restrict__ A, const ushort_t* __restrict__ B,
              float* __restrict__ Cp, int M, int N, int K) {
  __shared__ __align__(16) ushort_t As[2][128 * 64];
  __shared__ __align__(16) ushort_t Bs[2][128 * 64];
  const int tid = threadIdx.x;
  const int wave = tid >> 6, lane = tid & 63;
  const int wr = wave >> 1, wc = wave & 1;
  const int frow = lane & 15, g = lane >> 4;
  const int r8 = lane >> 3, c8 = lane & 7;
  const int m0 = blockIdx.x * 128, n0 = blockIdx.y * 128;

  f32x4 acc[4][4] = {};

  const int sc = (c8 ^ r8) << 3;
  const ushort_t* Ab = A + (size_t)(m0 + wave * 32 + r8) * K + sc;
  const ushort_t* Bb = B + (size_t)(n0 + wave * 32 + r8) * K + sc;

  auto stage = [&](int t, int sel) {
    ushort_t* AsW = &As[sel][(wave * 32) * 64];
    ushort_t* BsW = &Bs[sel][(wave * 32) * 64];
#pragma unroll
    for (int j = 0; j < 4; ++j) {
      gload16(AsW + j * 8 * 64, Ab + (size_t)j * 8 * K + t * 64);
      gload16(BsW + j * 8 * 64, Bb + (size_t)j * 8 * K + t * 64);
    }
  };

  stage(0, 0);
  __syncthreads();

  const int NT = K / 64;
  for (int t = 0; t < NT; ++t) {
    const int cur = t & 1;
    if (t < NT - 1) stage(t + 1, cur ^ 1);

    bf16x8 af[4][2], bfr[4][2];
#pragma unroll
    for (int mi = 0; mi < 4; ++mi) {
      int row = wr * 64 + mi * 16 + frow;
#pragma unroll
      for (int ki = 0; ki < 2; ++ki)
        af[mi][ki] = *(const bf16x8*)&As[cur][row * 64 + (((ki * 4 + g) ^ (row & 7)) << 3)];
    }
#pragma unroll
    for (int nf = 0; nf < 4; ++nf) {
      int row = wc * 64 + nf * 16 + frow;
#pragma unroll
      for (int ki = 0; ki < 2; ++ki)
        bfr[nf][ki] = *(const bf16x8*)&Bs[cur][row * 64 + (((ki * 4 + g) ^ (row & 7)) << 3)];
    }
#pragma unroll
    for (int ki = 0; ki < 2; ++ki)
#pragma unroll
      for (int mi = 0; mi < 4; ++mi)
#pragma unroll
        for (int nf = 0; nf < 4; ++nf)
          acc[mi][nf] = __builtin_amdgcn_mfma_f32_16x16x32_bf16(
              af[mi][ki], bfr[nf][ki], acc[mi][nf], 0, 0, 0);

    __syncthreads();
  }

#pragma unroll
  for (int mi = 0; mi < 4; ++mi)
#pragma unroll
    for (int nf = 0; nf < 4; ++nf)
#pragma unroll
      for (int r = 0; r < 4; ++r) {
        int m = m0 + wr * 64 + mi * 16 + g * 4 + r;
        int n = n0 + wc * 64 + nf * 16 + frow;
        Cp[(size_t)m * N + n] = acc[mi][nf][r];
      }
}

// ---------------- flash attention: 32x32 MFMA, P in registers ----------------
// R6-exact body (green lineage) + two component-proven grafts:
//  (a) QUAD-buffered K/V: same 64x64 tile layout/addressing, 4 buffers
//      indexed kt&3, prefetch 2 tiles per barrier -> 17 barriers vs 33.
//      WAR-safe: pair p's buffers are fully read before the pair-(p+1)
//      barrier that precedes their overwrite.
//  (b) ones-MFMA rowsum (proven R7/R14): lones[qb] shares oacc's D
//      row-mapping -> epilogue is a per-register divide; removes 64
//      fadds/tile/wave + all epilogue shuffles.
// Geometry/bounds untouched: 4 waves x 2 q-subtiles, 256 q/block, grid 512,
// XCD-bijective swizzle, launch_bounds(256,2) (R7/R10: never raise it).
__global__ __launch_bounds__(256, 2)
void attn_kernel(const ushort_t* __restrict__ Qp, const ushort_t* __restrict__ Kp,
                 const ushort_t* __restrict__ Vt, ushort_t* __restrict__ Xb) {
  __shared__ __align__(16) ushort_t Ks[4][64 * 64];   // [buf][key][d] swizzled
  __shared__ __align__(16) ushort_t Vs[4][64 * 64];   // [buf][d][key] swizzled

  const int tid = threadIdx.x;
  const int wave = tid >> 6, lane = tid & 63;
  const int l31 = lane & 31, h = lane >> 5;
  const int f8 = lane >> 3, c8 = lane & 7;

  const int d = blockIdx.x;                 // 0..511
  const int bh = ((d >> 6) << 3) | (d & 7); // same-head blocks share d%8 -> same XCD
  const int qt = (d >> 3) & 7;
  const int b = bh >> 4, hd = bh & 15;
  const int q0 = qt * 256 + wave * 64;

  // Q fragments: qf[qb][ki] = Q[q0+32qb+l31][hd*64 + 16ki + 8h .. +7]
  bf16x8 qf[2][4];
  {
    const ushort_t* qb_ = Qp + (size_t)(b * 2048 + q0 + l31) * 1024 + hd * 64 + 8 * h;
#pragma unroll
    for (int qb = 0; qb < 2; ++qb)
#pragma unroll
      for (int ki = 0; ki < 4; ++ki)
        qf[qb][ki] = *(const bf16x8*)(qb_ + (size_t)(qb * 32) * 1024 + 16 * ki);
  }

  const short one_bf = (short)0x3F80;
  const bf16x8 vones = {one_bf, one_bf, one_bf, one_bf,
                        one_bf, one_bf, one_bf, one_bf};

  f32x16 oacc[2][2] = {};
  f32x16 lones[2] = {};

  const ushort_t* Kbase = Kp + (size_t)(b * 2048) * 1024 + hd * 64;
  const ushort_t* Vbase = Vt + ((size_t)(bh * 64) << 11);

  auto stage = [&](int kt, int sel) {
#pragma unroll
    for (int j = 0; j < 2; ++j) {
      int row = wave * 16 + j * 8 + f8;  // row&7 == f8
      gload16(&Ks[sel][(wave * 16 + j * 8) * 64],
              Kbase + (size_t)(kt * 64 + row) * 1024 + ((c8 ^ f8) << 3));
      gload16(&Vs[sel][(wave * 16 + j * 8) * 64],
              Vbase + ((size_t)row << 11) + kt * 64 + ((c8 ^ f8) << 3));
    }
  };

  stage(0, 0);
  stage(1, 1);

  for (int kt = 0; kt < 32; ++kt) {
    if ((kt & 1) == 0) {
      __syncthreads();                 // tiles kt, kt+1 landed; pair bufs free
      if (kt < 30) {
        stage(kt + 2, (kt + 2) & 3);   // prefetch next pair under this pair's compute
        stage(kt + 3, (kt + 3) & 3);
      }
    }
    const int cur = kt & 3;

    // K frags: kf[c][ki] = K[32c+l31][16ki+8h..+7] (A-operand, row=key)
    bf16x8 kf[2][4];
#pragma unroll
    for (int c = 0; c < 2; ++c)
#pragma unroll
      for (int ki = 0; ki < 4; ++ki) {
        int row = c * 32 + l31;
        kf[c][ki] = *(const bf16x8*)&Ks[cur][row * 64 + (((2 * ki + h) ^ (row & 7)) << 3)];
      }
    // V frags: vf[kc][db] = V[16kc+8h..+7][32db+l31] (B-operand) from Vs[d][key]
    bf16x8 vf[4][2];
#pragma unroll
    for (int kc = 0; kc < 4; ++kc)
#pragma unroll
      for (int db = 0; db < 2; ++db) {
        int row = db * 32 + l31;
        vf[kc][db] = *(const bf16x8*)&Vs[cur][row * 64 + (((2 * kc + h) ^ (row & 7)) << 3)];
      }

#pragma unroll
    for (int qb = 0; qb < 2; ++qb) {
      // S^T[key][q]: D col=q=l31, row=key=(reg&3)+8*(reg>>2)+4h+32c
      f32x16 sacc[2];
      __builtin_amdgcn_s_setprio(1);
#pragma unroll
      for (int c = 0; c < 2; ++c) {
        sacc[c] = __builtin_amdgcn_mfma_f32_32x32x16_bf16(
            kf[c][0], qf[qb][0], (f32x16)(0.0f), 0, 0, 0);
#pragma unroll
        for (int ki = 1; ki < 4; ++ki)
          sacc[c] = __builtin_amdgcn_mfma_f32_32x32x16_bf16(
              kf[c][ki], qf[qb][ki], sacc[c], 0, 0, 0);
      }
      __builtin_amdgcn_s_setprio(0);

      // p = exp2(s) in place (row sums come free from the ones-MFMA below)
#pragma unroll
      for (int c = 0; c < 2; ++c)
#pragma unroll
        for (int r = 0; r < 16; r += 4) {
          sacc[c][r]     = fast_exp2(sacc[c][r]);
          sacc[c][r + 1] = fast_exp2(sacc[c][r + 1]);
          sacc[c][r + 2] = fast_exp2(sacc[c][r + 2]);
          sacc[c][r + 3] = fast_exp2(sacc[c][r + 3]);
        }

      // lane holds 4-elem halves (offset 4h) of every 8-key block;
      // swap even/odd-block halves with partner lane l^32 -> consecutive 8.
      bf16x8 pfrag[4];
#pragma unroll
      for (int kc = 0; kc < 4; ++kc) {
        const int e = 2 * kc, o = 2 * kc + 1;
        const int ce = e >> 2, me = e & 3, co = o >> 2, mo = o & 3;
        unsigned x0, x1, y0, y1;
        x0 = cvt_pk(sacc[ce][4 * me],     sacc[ce][4 * me + 1]);
        x1 = cvt_pk(sacc[ce][4 * me + 2], sacc[ce][4 * me + 3]);
        y0 = cvt_pk(sacc[co][4 * mo],     sacc[co][4 * mo + 1]);
        y1 = cvt_pk(sacc[co][4 * mo + 2], sacc[co][4 * mo + 3]);
        asm("v_permlane32_swap_b32 %0, %1" : "+v"(x0), "+v"(y0));
        asm("v_permlane32_swap_b32 %0, %1" : "+v"(x1), "+v"(y1));
        uint4v pu; pu[0] = x0; pu[1] = x1; pu[2] = y0; pu[3] = y1;
        pfrag[kc] = __builtin_bit_cast(bf16x8, pu);
      }

      // O[q][d] += P V ; rowsum l += P * ones (same D row-mapping as oacc)
      __builtin_amdgcn_s_setprio(1);
#pragma unroll
      for (int kc = 0; kc < 4; ++kc) {
        oacc[qb][0] = __builtin_amdgcn_mfma_f32_32x32x16_bf16(
            pfrag[kc], vf[kc][0], oacc[qb][0], 0, 0, 0);
        oacc[qb][1] = __builtin_amdgcn_mfma_f32_32x32x16_bf16(
            pfrag[kc], vf[kc][1], oacc[qb][1], 0, 0, 0);
        lones[qb] = __builtin_amdgcn_mfma_f32_32x32x16_bf16(
            pfrag[kc], vones, lones[qb], 0, 0, 0);
      }
      __builtin_amdgcn_s_setprio(0);
    }
  }

  // epilogue: per-register divide (lones row mapping == oacc row mapping)
#pragma unroll
  for (int qb = 0; qb < 2; ++qb) {
    float linv[16];
#pragma unroll
    for (int r = 0; r < 16; ++r) linv[r] = 1.0f / lones[qb][r];
#pragma unroll
    for (int db = 0; db < 2; ++db)
#pragma unroll
      for (int r = 0; r < 16; ++r) {
        int qrow = (r & 3) + 8 * (r >> 2) + 4 * h;   // D-row = q-local
        int grow = b * 2048 + q0 + qb * 32 + qrow;
        int gcol = hd * 64 + db * 32 + l31;
        Xb[(size_t)grow * 1024 + gcol] = f2bf(oacc[qb][db][r] * linv[r]);
      }
  }
}

// ---------------- launch ----------------
extern "C" void kernel_launch(void* const* d_in, const int* in_sizes, int n_in,
                              void* d_out, int out_size, void* d_ws, size_t ws_size,
                              hipStream_t stream) {
  const float* q = (const float*)d_in[0];
  const float* k = (const float*)d_in[1];
  const float* v = (const float*)d_in[2];
  const float* wq = (const float*)d_in[3];
  const float* wk = (const float*)d_in[4];
  const float* wv = (const float*)d_in[5];
  const float* wo = (const float*)d_in[6];

  const int M = 8192, D = 1024;
  const size_t MD = (size_t)M * D;
  const size_t DD = (size_t)D * D;

  ushort_t* ws = (ushort_t*)d_ws;
  ushort_t* buf0 = ws;             // attn output
  ushort_t* Qp = buf0 + MD;        // Qp, Kp contiguous (qkv_gemm z<2)
  ushort_t* Kp = Qp + MD;
  ushort_t* Vt = Kp + MD;
  ushort_t* wqb = Vt + MD;         // 4 weight buffers contiguous
  ushort_t* wob = wqb + 3 * DD;

  // weights -> bf16 (one launch)
  {
    int n4 = (int)(DD / 4);
    dim3 gw((n4 + 255) / 256, 4);
    cast_w4<<<gw, 256, 0, stream>>>(wq, wk, wv, wo, wqb, n4);
  }

  // fused Q/K/V projections: grid (64,8,3) = 1536 blocks
  {
    dim3 gq(M / 128, D / 128, 3);
    qkv_gemm<<<gq, 256, 0, stream>>>(q, k, v, wqb, Qp, Vt,
                                     0.125f * 1.44269504f);
  }

  // attention -> buf0 (bf16); 1D grid 512 with XCD swizzle
  attn_kernel<<<512, 256, 0, stream>>>(Qp, Kp, Vt, buf0);

  // output projection -> f32 out
  dim3 gg(M / 128, D / 128);
  gemm_out<<<gg, 256, 0, stream>>>(buf0, wob, (float*)d_out, M, D, D);
}

// Round 16
// 187.989 us; speedup vs baseline: 1.1282x; 1.0532x over previous
//
#include <hip/hip_runtime.h>

typedef unsigned short ushort_t;
typedef __attribute__((ext_vector_type(8))) short bf16x8;
typedef __attribute__((ext_vector_type(4))) float f32x4;
typedef __attribute__((ext_vector_type(16))) float f32x16;
typedef __attribute__((ext_vector_type(4))) unsigned short ushort4v;
typedef __attribute__((ext_vector_type(4))) unsigned int uint4v;

__device__ __forceinline__ ushort_t f2bf(float f) {
  unsigned u = __float_as_uint(f);
  u += 0x7FFFu + ((u >> 16) & 1u);
  return (ushort_t)(u >> 16);
}

__device__ __forceinline__ unsigned cvt_pk(float lo, float hi) {
  unsigned r;
  asm("v_cvt_pk_bf16_f32 %0, %1, %2" : "=v"(r) : "v"(lo), "v"(hi));
  return r;
}

__device__ __forceinline__ float fast_exp2(float x) {
  float r;
  asm("v_exp_f32 %0, %1" : "=v"(r) : "v"(x));
  return r;
}

__device__ __forceinline__ void gload16(ushort_t* lds, const ushort_t* g) {
  __builtin_amdgcn_global_load_lds(
      (const __attribute__((address_space(1))) unsigned int*)g,
      (__attribute__((address_space(3))) unsigned int*)lds, 16, 0, 0);
}

// ---------------- weight cast (4 tensors, one launch) ----------------
__global__ void cast_w4(const float* __restrict__ s0, const float* __restrict__ s1,
                        const float* __restrict__ s2, const float* __restrict__ s3,
                        ushort_t* __restrict__ dst, int n4) {
  int i = blockIdx.x * blockDim.x + threadIdx.x;
  if (i >= n4) return;
  int z = blockIdx.y;
  const float* s = (z == 0) ? s0 : (z == 1) ? s1 : (z == 2) ? s2 : s3;
  float4 f = ((const float4*)s)[i];
  ushort4v o;
  o.x = f2bf(f.x); o.y = f2bf(f.y); o.z = f2bf(f.z); o.w = f2bf(f.w);
  ((ushort4v*)(dst + (size_t)z * n4 * 4))[i] = o;
}

// ---------------- fused QKV projection GEMM ----------------
// z = blockIdx.z selects {q,k,v}: C[m,n] = scale_z * sum_k A_z[m,k]*W_z[n,k].
// A_z f32 (fused cast in staging); W contiguous at Wb + z*DD.
// z<2: bf16 C to QKp + z*MD; z==2: V^T-per-head layout to Vt.
// Grid (64,8,3) = 1536 blocks -> 6 blocks/CU (vs 3 x 512-block launches).
__global__ __launch_bounds__(256, 2)
void qkv_gemm(const float* __restrict__ qa, const float* __restrict__ ka,
              const float* __restrict__ va, const ushort_t* __restrict__ Wb,
              ushort_t* __restrict__ QKp, ushort_t* __restrict__ Vt,
              float qscale) {
  const int M = 8192, N = 1024, K = 1024;
  __shared__ __align__(16) ushort_t As[128 * 64];
  __shared__ __align__(16) ushort_t Bs[128 * 64];
  const int tid = threadIdx.x;
  const int wave = tid >> 6, lane = tid & 63;
  const int wr = wave >> 1, wc = wave & 1;
  const int frow = lane & 15, g = lane >> 4;
  const int r8 = lane >> 3, c8 = lane & 7;
  const int m0 = blockIdx.x * 128, n0 = blockIdx.y * 128;
  const int z = blockIdx.z;

  const float* Asrc = (z == 0) ? qa : (z == 1) ? ka : va;
  const float scale = (z == 0) ? qscale : 1.0f;

  f32x4 acc[4][4] = {};

  const int sc = (c8 ^ r8) << 3;  // pre-swizzled source chunk offset (elems)
  const ushort_t* Bb = Wb + (size_t)z * N * K + (size_t)(n0 + wave * 32 + r8) * K + sc;
  ushort_t* AsW = &As[(wave * 32) * 64];
  ushort_t* BsW = &Bs[(wave * 32) * 64];

  const float* Af = Asrc + (size_t)(m0 + wave * 32 + r8) * K + sc;
  float a_pre[32];
#pragma unroll
  for (int j = 0; j < 4; ++j) {
    *(float4*)&a_pre[j * 8]     = *(const float4*)(Af + (size_t)j * 8 * K);
    *(float4*)&a_pre[j * 8 + 4] = *(const float4*)(Af + (size_t)j * 8 * K + 4);
  }

  for (int kt = 0; kt < K; kt += 64) {
    __syncthreads();
#pragma unroll
    for (int j = 0; j < 4; ++j) {
      uint4v w;
      w[0] = cvt_pk(a_pre[j * 8 + 0], a_pre[j * 8 + 1]);
      w[1] = cvt_pk(a_pre[j * 8 + 2], a_pre[j * 8 + 3]);
      w[2] = cvt_pk(a_pre[j * 8 + 4], a_pre[j * 8 + 5]);
      w[3] = cvt_pk(a_pre[j * 8 + 6], a_pre[j * 8 + 7]);
      *(uint4v*)&AsW[j * 8 * 64 + lane * 8] = w;
      gload16(BsW + j * 8 * 64, Bb + (size_t)j * 8 * K + kt);
    }
    __syncthreads();

    if (kt + 64 < K) {  // prefetch next f32 A-tile; consumed after next barrier
#pragma unroll
      for (int j = 0; j < 4; ++j) {
        *(float4*)&a_pre[j * 8]     = *(const float4*)(Af + (size_t)j * 8 * K + kt + 64);
        *(float4*)&a_pre[j * 8 + 4] = *(const float4*)(Af + (size_t)j * 8 * K + kt + 68);
      }
    }

    bf16x8 af[4][2], bfr[4][2];
#pragma unroll
    for (int mi = 0; mi < 4; ++mi) {
      int row = wr * 64 + mi * 16 + frow;
#pragma unroll
      for (int ki = 0; ki < 2; ++ki)
        af[mi][ki] = *(const bf16x8*)&As[row * 64 + (((ki * 4 + g) ^ (row & 7)) << 3)];
    }
#pragma unroll
    for (int nf = 0; nf < 4; ++nf) {
      int row = wc * 64 + nf * 16 + frow;
#pragma unroll
      for (int ki = 0; ki < 2; ++ki)
        bfr[nf][ki] = *(const bf16x8*)&Bs[row * 64 + (((ki * 4 + g) ^ (row & 7)) << 3)];
    }
#pragma unroll
    for (int ki = 0; ki < 2; ++ki)
#pragma unroll
      for (int mi = 0; mi < 4; ++mi)
#pragma unroll
        for (int nf = 0; nf < 4; ++nf)
          acc[mi][nf] = __builtin_amdgcn_mfma_f32_16x16x32_bf16(
              af[mi][ki], bfr[nf][ki], acc[mi][nf], 0, 0, 0);
  }

#pragma unroll
  for (int mi = 0; mi < 4; ++mi)
#pragma unroll
    for (int nf = 0; nf < 4; ++nf)
#pragma unroll
      for (int r = 0; r < 4; ++r) {
        int m = m0 + wr * 64 + mi * 16 + g * 4 + r;
        int n = n0 + wc * 64 + nf * 16 + frow;
        float v = acc[mi][nf][r] * scale;
        if (z == 2) {
          int b = m >> 11, s = m & 2047, h = n >> 6, dk = n & 63;
          Vt[(((size_t)((b * 16 + h) * 64 + dk)) << 11) + s] = f2bf(v);
        } else {
          QKp[(size_t)z * M * N + (size_t)m * N + n] = f2bf(v);
        }
      }
}

// ---------------- output projection GEMM (bf16 A, f32 C) ----------------
__global__ __launch_bounds__(256, 2)
void gemm_out(const ushort_t* __restrict__ A, const ushort_t* __restrict__ B,
              float* __restrict__ Cp, int M, int N, int K) {
  __shared__ __align__(16) ushort_t As[128 * 64];
  __shared__ __align__(16) ushort_t Bs[128 * 64];
  const int tid = threadIdx.x;
  const int wave = tid >> 6, lane = tid & 63;
  const int wr = wave >> 1, wc = wave & 1;
  const int frow = lane & 15, g = lane >> 4;
  const int r8 = lane >> 3, c8 = lane & 7;
  const int m0 = blockIdx.x * 128, n0 = blockIdx.y * 128;

  f32x4 acc[4][4] = {};

  const int sc = (c8 ^ r8) << 3;
  const ushort_t* Ab = A + (size_t)(m0 + wave * 32 + r8) * K + sc;
  const ushort_t* Bb = B + (size_t)(n0 + wave * 32 + r8) * K + sc;
  ushort_t* AsW = &As[(wave * 32) * 64];
  ushort_t* BsW = &Bs[(wave * 32) * 64];

  for (int kt = 0; kt < K; kt += 64) {
    __syncthreads();
#pragma unroll
    for (int j = 0; j < 4; ++j) {
      gload16(AsW + j * 8 * 64, Ab + (size_t)j * 8 * K + kt);
      gload16(BsW + j * 8 * 64, Bb + (size_t)j * 8 * K + kt);
    }
    __syncthreads();

    bf16x8 af[4][2], bfr[4][2];
#pragma unroll
    for (int mi = 0; mi < 4; ++mi) {
      int row = wr * 64 + mi * 16 + frow;
#pragma unroll
      for (int ki = 0; ki < 2; ++ki)
        af[mi][ki] = *(const bf16x8*)&As[row * 64 + (((ki * 4 + g) ^ (row & 7)) << 3)];
    }
#pragma unroll
    for (int nf = 0; nf < 4; ++nf) {
      int row = wc * 64 + nf * 16 + frow;
#pragma unroll
      for (int ki = 0; ki < 2; ++ki)
        bfr[nf][ki] = *(const bf16x8*)&Bs[row * 64 + (((ki * 4 + g) ^ (row & 7)) << 3)];
    }
#pragma unroll
    for (int ki = 0; ki < 2; ++ki)
#pragma unroll
      for (int mi = 0; mi < 4; ++mi)
#pragma unroll
        for (int nf = 0; nf < 4; ++nf)
          acc[mi][nf] = __builtin_amdgcn_mfma_f32_16x16x32_bf16(
              af[mi][ki], bfr[nf][ki], acc[mi][nf], 0, 0, 0);
  }

#pragma unroll
  for (int mi = 0; mi < 4; ++mi)
#pragma unroll
    for (int nf = 0; nf < 4; ++nf)
#pragma unroll
      for (int r = 0; r < 4; ++r) {
        int m = m0 + wr * 64 + mi * 16 + g * 4 + r;
        int n = n0 + wc * 64 + nf * 16 + frow;
        Cp[(size_t)m * N + n] = acc[mi][nf][r];
      }
}

// ---------------- flash attention: 32x32 MFMA, P in registers ----------------
// R6-EXACT (validated green incl. post-timing, ~90us): 256 q-rows/block,
// 4 waves x 2 q-subtiles, KBLK=64 dbuf K/V, grid 512, XCD-bijective swizzle,
// launch_bounds(256,2) -> VGPR 112, no spill. Lessons (R7-R15): raising the
// min-waves bound spills accumulators; c-outer restructures race; quad-buffer
// + ones-MFMA rowsum measured negative. This body is the local optimum.
__global__ __launch_bounds__(256, 2)
void attn_kernel(const ushort_t* __restrict__ Qp, const ushort_t* __restrict__ Kp,
                 const ushort_t* __restrict__ Vt, ushort_t* __restrict__ Xb) {
  __shared__ __align__(16) ushort_t Ks[2][64 * 64];   // [buf][key][d] swizzled
  __shared__ __align__(16) ushort_t Vs[2][64 * 64];   // [buf][d][key] swizzled

  const int tid = threadIdx.x;
  const int wave = tid >> 6, lane = tid & 63;
  const int l31 = lane & 31, h = lane >> 5;
  const int f8 = lane >> 3, c8 = lane & 7;

  const int d = blockIdx.x;                 // 0..511
  const int bh = ((d >> 6) << 3) | (d & 7); // same-head blocks share d%8 -> same XCD
  const int qt = (d >> 3) & 7;
  const int b = bh >> 4, hd = bh & 15;
  const int q0 = qt * 256 + wave * 64;

  // Q fragments: qf[qb][ki] = Q[q0+32qb+l31][hd*64 + 16ki + 8h .. +7]
  bf16x8 qf[2][4];
  {
    const ushort_t* qb_ = Qp + (size_t)(b * 2048 + q0 + l31) * 1024 + hd * 64 + 8 * h;
#pragma unroll
    for (int qb = 0; qb < 2; ++qb)
#pragma unroll
      for (int ki = 0; ki < 4; ++ki)
        qf[qb][ki] = *(const bf16x8*)(qb_ + (size_t)(qb * 32) * 1024 + 16 * ki);
  }

  f32x16 oacc[2][2] = {};
  float ls[2][4] = {};

  const ushort_t* Kbase = Kp + (size_t)(b * 2048) * 1024 + hd * 64;
  const ushort_t* Vbase = Vt + ((size_t)(bh * 64) << 11);

  auto stage = [&](int kt, int sel) {
#pragma unroll
    for (int j = 0; j < 2; ++j) {
      int row = wave * 16 + j * 8 + f8;  // row&7 == f8
      gload16(&Ks[sel][(wave * 16 + j * 8) * 64],
              Kbase + (size_t)(kt * 64 + row) * 1024 + ((c8 ^ f8) << 3));
      gload16(&Vs[sel][(wave * 16 + j * 8) * 64],
              Vbase + ((size_t)row << 11) + kt * 64 + ((c8 ^ f8) << 3));
    }
  };

  stage(0, 0);

  for (int kt = 0; kt < 32; ++kt) {
    const int cur = kt & 1;
    __syncthreads();                       // vmcnt(0) drain: stage(kt) landed
    if (kt < 31) stage(kt + 1, cur ^ 1);   // prefetch under compute

    // K frags: kf[c][ki] = K[32c+l31][16ki+8h..+7] (A-operand, row=key)
    bf16x8 kf[2][4];
#pragma unroll
    for (int c = 0; c < 2; ++c)
#pragma unroll
      for (int ki = 0; ki < 4; ++ki) {
        int row = c * 32 + l31;
        kf[c][ki] = *(const bf16x8*)&Ks[cur][row * 64 + (((2 * ki + h) ^ (row & 7)) << 3)];
      }
    // V frags: vf[kc][db] = V[16kc+8h..+7][32db+l31] (B-operand) from Vs[d][key]
    bf16x8 vf[4][2];
#pragma unroll
    for (int kc = 0; kc < 4; ++kc)
#pragma unroll
      for (int db = 0; db < 2; ++db) {
        int row = db * 32 + l31;
        vf[kc][db] = *(const bf16x8*)&Vs[cur][row * 64 + (((2 * kc + h) ^ (row & 7)) << 3)];
      }

#pragma unroll
    for (int qb = 0; qb < 2; ++qb) {
      // S^T[key][q]: D col=q=l31, row=key=(reg&3)+8*(reg>>2)+4h+32c
      f32x16 sacc[2];
      __builtin_amdgcn_s_setprio(1);
#pragma unroll
      for (int c = 0; c < 2; ++c) {
        sacc[c] = __builtin_amdgcn_mfma_f32_32x32x16_bf16(
            kf[c][0], qf[qb][0], (f32x16)(0.0f), 0, 0, 0);
#pragma unroll
        for (int ki = 1; ki < 4; ++ki)
          sacc[c] = __builtin_amdgcn_mfma_f32_32x32x16_bf16(
              kf[c][ki], qf[qb][ki], sacc[c], 0, 0, 0);
      }
      __builtin_amdgcn_s_setprio(0);

      // p = exp2(s) in place; 4 independent partial sums (no FP-serial chain)
#pragma unroll
      for (int c = 0; c < 2; ++c)
#pragma unroll
        for (int r = 0; r < 16; r += 4) {
          float p0 = fast_exp2(sacc[c][r]);
          float p1 = fast_exp2(sacc[c][r + 1]);
          float p2 = fast_exp2(sacc[c][r + 2]);
          float p3 = fast_exp2(sacc[c][r + 3]);
          sacc[c][r] = p0; sacc[c][r + 1] = p1;
          sacc[c][r + 2] = p2; sacc[c][r + 3] = p3;
          ls[qb][0] += p0; ls[qb][1] += p1; ls[qb][2] += p2; ls[qb][3] += p3;
        }

      // lane holds 4-elem halves (offset 4h) of every 8-key block;
      // swap even/odd-block halves with partner lane l^32 -> consecutive 8.
      bf16x8 pfrag[4];
#pragma unroll
      for (int kc = 0; kc < 4; ++kc) {
        const int e = 2 * kc, o = 2 * kc + 1;
        const int ce = e >> 2, me = e & 3, co = o >> 2, mo = o & 3;
        unsigned x0, x1, y0, y1;
        x0 = cvt_pk(sacc[ce][4 * me],     sacc[ce][4 * me + 1]);
        x1 = cvt_pk(sacc[ce][4 * me + 2], sacc[ce][4 * me + 3]);
        y0 = cvt_pk(sacc[co][4 * mo],     sacc[co][4 * mo + 1]);
        y1 = cvt_pk(sacc[co][4 * mo + 2], sacc[co][4 * mo + 3]);
        asm("v_permlane32_swap_b32 %0, %1" : "+v"(x0), "+v"(y0));
        asm("v_permlane32_swap_b32 %0, %1" : "+v"(x1), "+v"(y1));
        uint4v pu; pu[0] = x0; pu[1] = x1; pu[2] = y0; pu[3] = y1;
        pfrag[kc] = __builtin_bit_cast(bf16x8, pu);
      }

      // O[q][d] += P V : A=pfrag (row=q=l31), B=vf
      __builtin_amdgcn_s_setprio(1);
#pragma unroll
      for (int kc = 0; kc < 4; ++kc)
#pragma unroll
        for (int db = 0; db < 2; ++db)
          oacc[qb][db] = __builtin_amdgcn_mfma_f32_32x32x16_bf16(
              pfrag[kc], vf[kc][db], oacc[qb][db], 0, 0, 0);
      __builtin_amdgcn_s_setprio(0);
    }
  }

  // epilogue: combine partner half-key sums, broadcast 1/l, store
#pragma unroll
  for (int qb = 0; qb < 2; ++qb) {
    float lsum = (ls[qb][0] + ls[qb][1]) + (ls[qb][2] + ls[qb][3]);
    float lf = lsum + __shfl_xor(lsum, 32, 64);
    float linv = 1.0f / lf;                 // valid at lanes with l31 == q
#pragma unroll
    for (int db = 0; db < 2; ++db)
#pragma unroll
      for (int r = 0; r < 16; ++r) {
        int qrow = (r & 3) + 8 * (r >> 2) + 4 * h;   // D-row = q-local
        float li = __shfl(linv, qrow, 64);
        int grow = b * 2048 + q0 + qb * 32 + qrow;
        int gcol = hd * 64 + db * 32 + l31;
        Xb[(size_t)grow * 1024 + gcol] = f2bf(oacc[qb][db][r] * li);
      }
  }
}

// ---------------- launch ----------------
extern "C" void kernel_launch(void* const* d_in, const int* in_sizes, int n_in,
                              void* d_out, int out_size, void* d_ws, size_t ws_size,
                              hipStream_t stream) {
  const float* q = (const float*)d_in[0];
  const float* k = (const float*)d_in[1];
  const float* v = (const float*)d_in[2];
  const float* wq = (const float*)d_in[3];
  const float* wk = (const float*)d_in[4];
  const float* wv = (const float*)d_in[5];
  const float* wo = (const float*)d_in[6];

  const int M = 8192, D = 1024;
  const size_t MD = (size_t)M * D;
  const size_t DD = (size_t)D * D;

  ushort_t* ws = (ushort_t*)d_ws;
  ushort_t* buf0 = ws;             // attn output
  ushort_t* Qp = buf0 + MD;        // Qp, Kp contiguous (qkv_gemm z<2)
  ushort_t* Kp = Qp + MD;
  ushort_t* Vt = Kp + MD;
  ushort_t* wqb = Vt + MD;         // 4 weight buffers contiguous
  ushort_t* wob = wqb + 3 * DD;

  // weights -> bf16 (one launch)
  {
    int n4 = (int)(DD / 4);
    dim3 gw((n4 + 255) / 256, 4);
    cast_w4<<<gw, 256, 0, stream>>>(wq, wk, wv, wo, wqb, n4);
  }

  // fused Q/K/V projections: grid (64,8,3) = 1536 blocks
  {
    dim3 gq(M / 128, D / 128, 3);
    qkv_gemm<<<gq, 256, 0, stream>>>(q, k, v, wqb, Qp, Vt,
                                     0.125f * 1.44269504f);
  }

  // attention -> buf0 (bf16); 1D grid 512 with XCD swizzle
  attn_kernel<<<512, 256, 0, stream>>>(Qp, Kp, Vt, buf0);

  // output projection -> f32 out
  dim3 gg(M / 128, D / 128);
  gemm_out<<<gg, 256, 0, stream>>>(buf0, wob, (float*)d_out, M, D, D);
}